// Round 2
// baseline (836.812 us; speedup 1.0000x reference)
//
#include <hip/hip_runtime.h>

#define NCHW_C   64
#define IMG_H    500
#define IMG_W    500
#define NH       63
#define NW       63

// Orthonormal 8x8 DCT-II matrix (double-precision-derived literals).
static __constant__ float D8[8][8] = {
  {0.35355339059327373f, 0.35355339059327373f, 0.35355339059327373f, 0.35355339059327373f,
   0.35355339059327373f, 0.35355339059327373f, 0.35355339059327373f, 0.35355339059327373f},
  {0.49039264020161522f, 0.41573480615127262f, 0.27778511650980114f, 0.09754516100806417f,
  -0.09754516100806417f,-0.27778511650980114f,-0.41573480615127262f,-0.49039264020161522f},
  {0.46193976625564337f, 0.19134171618254492f,-0.19134171618254492f,-0.46193976625564337f,
  -0.46193976625564337f,-0.19134171618254492f, 0.19134171618254492f, 0.46193976625564337f},
  {0.41573480615127262f,-0.09754516100806417f,-0.49039264020161522f,-0.27778511650980114f,
   0.27778511650980114f, 0.49039264020161522f, 0.09754516100806417f,-0.41573480615127262f},
  {0.35355339059327373f,-0.35355339059327373f,-0.35355339059327373f, 0.35355339059327373f,
   0.35355339059327373f,-0.35355339059327373f,-0.35355339059327373f, 0.35355339059327373f},
  {0.27778511650980114f,-0.49039264020161522f, 0.09754516100806417f, 0.41573480615127262f,
  -0.41573480615127262f,-0.09754516100806417f, 0.49039264020161522f,-0.27778511650980114f},
  {0.19134171618254492f,-0.46193976625564337f, 0.46193976625564337f,-0.19134171618254492f,
  -0.19134171618254492f, 0.46193976625564337f,-0.46193976625564337f, 0.19134171618254492f},
  {0.09754516100806417f,-0.27778511650980114f, 0.41573480615127262f,-0.49039264020161522f,
   0.49039264020161522f,-0.41573480615127262f, 0.27778511650980114f,-0.09754516100806417f},
};

// One workgroup (256 threads) handles one (n, c, block-row i):
//   stage 8 x 504 input strip (reflect-padded) into LDS with coalesced
//   float4 loads, then 4 threads per 8x8 block compute D * X * D^T; each
//   thread produces 2 contiguous output rows (64 B) -> 4x float4 stores.
__global__ __launch_bounds__(256)
void blockdct_kernel(const float* __restrict__ x, float* __restrict__ out) {
    __shared__ float lds[8][504];

    const int tid = threadIdx.x;
    const int wg  = blockIdx.x;
    const int i   = wg % NH;         // block-row index
    const int nc  = wg / NH;         // n*C + c
    const int r0  = i * 8;

    const float* __restrict__ src = x + (size_t)nc * ((size_t)IMG_H * IMG_W);

    // ---- Phase 1: coalesced float4 loads of the 8 x 500 region ----
    for (int t = tid; t < 8 * 125; t += 256) {
        const int b = t / 125;
        const int v = t - b * 125;
        int r = r0 + b;
        if (r >= IMG_H) r = 2 * IMG_H - 2 - r;      // reflect (no edge repeat)
        const float4 val = *(const float4*)(src + (size_t)r * IMG_W + (size_t)v * 4);
        *(float4*)&lds[b][v * 4] = val;
    }
    // tail columns 500..503 -> reflect to 498..495
    if (tid < 32) {
        const int b  = tid >> 2;
        const int cc = tid & 3;                      // padded col = 500 + cc
        int r = r0 + b;
        if (r >= IMG_H) r = 2 * IMG_H - 2 - r;
        lds[b][500 + cc] = src[(size_t)r * IMG_W + (498 - cc)];
    }
    __syncthreads();

    // ---- Phase 2: per-block DCT ----
    if (tid < 252) {
        const int j   = tid >> 2;                    // block col 0..62
        const int sub = tid & 3;                     // which pair of output rows
        const int a0  = sub * 2;

        // Select the two D rows for the left multiply with compile-time
        // indices (becomes cndmask-selected inline constants, no scattered
        // constant-memory loads).
        float da[8], db[8];
        #pragma unroll
        for (int b = 0; b < 8; ++b) {
            float va = D8[0][b], vb = D8[1][b];
            if (sub == 1) { va = D8[2][b]; vb = D8[3][b]; }
            if (sub == 2) { va = D8[4][b]; vb = D8[5][b]; }
            if (sub == 3) { va = D8[6][b]; vb = D8[7][b]; }
            da[b] = va; db[b] = vb;
        }

        float y0[8], y1[8];
        #pragma unroll
        for (int d = 0; d < 8; ++d) { y0[d] = 0.f; y1[d] = 0.f; }

        // y[a][d] = sum_b D[a][b] * X[b][d]
        #pragma unroll
        for (int b = 0; b < 8; ++b) {
            const float4 lo = *(const float4*)&lds[b][j * 8];
            const float4 hi = *(const float4*)&lds[b][j * 8 + 4];
            const float xr[8] = {lo.x, lo.y, lo.z, lo.w, hi.x, hi.y, hi.z, hi.w};
            #pragma unroll
            for (int d = 0; d < 8; ++d) {
                y0[d] = fmaf(da[b], xr[d], y0[d]);
                y1[d] = fmaf(db[b], xr[d], y1[d]);
            }
        }

        // z[a][e] = sum_d y[a][d] * D[e][d]   (compile-time D indices -> SGPRs)
        float z0[8], z1[8];
        #pragma unroll
        for (int e = 0; e < 8; ++e) {
            float s0 = 0.f, s1 = 0.f;
            #pragma unroll
            for (int d = 0; d < 8; ++d) {
                s0 = fmaf(y0[d], D8[e][d], s0);
                s1 = fmaf(y1[d], D8[e][d], s1);
            }
            z0[e] = s0; z1[e] = s1;
        }

        // Output block (n,c,i,j) is 64 contiguous floats; this thread owns a
        // contiguous 64 B slice of it.
        float* __restrict__ outp =
            out + ((size_t)nc * (NH * NW) + (size_t)i * NW + j) * 64 + a0 * 8;
        *(float4*)(outp + 0)  = make_float4(z0[0], z0[1], z0[2], z0[3]);
        *(float4*)(outp + 4)  = make_float4(z0[4], z0[5], z0[6], z0[7]);
        *(float4*)(outp + 8)  = make_float4(z1[0], z1[1], z1[2], z1[3]);
        *(float4*)(outp + 12) = make_float4(z1[4], z1[5], z1[6], z1[7]);
    }
}

extern "C" void kernel_launch(void* const* d_in, const int* in_sizes, int n_in,
                              void* d_out, int out_size, void* d_ws, size_t ws_size,
                              hipStream_t stream) {
    const float* x = (const float*)d_in[0];
    float* out = (float*)d_out;
    const int n_images = in_sizes[0] / (IMG_H * IMG_W);   // N*C = 512
    const int nwg = n_images * NH;                        // 32256 workgroups
    blockdct_kernel<<<nwg, 256, 0, stream>>>(x, out);
}